// Round 10
// baseline (389.357 us; speedup 1.0000x reference)
//
#include <hip/hip_runtime.h>

typedef unsigned short u16;
typedef __attribute__((ext_vector_type(8))) short bf16x8;
typedef __attribute__((ext_vector_type(4))) float f32x4;
typedef __attribute__((ext_vector_type(4))) u16 u16x4;
typedef __attribute__((ext_vector_type(8))) u16 u16x8;

__device__ __forceinline__ u16 f2bf(float f) {
    union { float f; unsigned u; } v; v.f = f;
    unsigned u = v.u;
    unsigned r = (u + 0x7fffu + ((u >> 16) & 1u)) >> 16;
    return (u16)r;
}
__device__ __forceinline__ float bf2f(u16 u) {
    union { unsigned u; float f; } v; v.u = ((unsigned)u) << 16;
    return v.f;
}

__device__ __forceinline__ void gload16(const u16* g, u16* l) {
    __builtin_amdgcn_global_load_lds((const __attribute__((address_space(1))) void*)g,
                                     (__attribute__((address_space(3))) void*)l, 16, 0, 0);
}

#define WAITV(N) asm volatile("s_waitcnt vmcnt(" #N ")" ::: "memory")

__device__ __forceinline__ void sbar() {
    __builtin_amdgcn_sched_barrier(0);
    __builtin_amdgcn_s_barrier();
    __builtin_amdgcn_sched_barrier(0);
}

// ---------------- merged leaves: weight cvt (blocks 0..5119) + BN0 partial stats ----------------
__device__ __forceinline__ void cvt4(const float* in, u16* out, int i) {
    f32x4 v = *(const f32x4*)(in + (size_t)i * 4);
    u16x4 o;
    o.x = f2bf(v.x); o.y = f2bf(v.y); o.z = f2bf(v.z); o.w = f2bf(v.w);
    *(u16x4*)(out + (size_t)i * 4) = o;
}

__global__ __launch_bounds__(256) void leaf_kernel(
    const float* __restrict__ W1, const float* __restrict__ W2, const float* __restrict__ W3,
    u16* __restrict__ W1b, u16* __restrict__ W2b, u16* __restrict__ W3b,
    const float* __restrict__ x, float* __restrict__ part0, int* __restrict__ cnt) {
    int bid = blockIdx.x;
    if (bid == 0 && threadIdx.x == 0) *cnt = 0;   // grid-barrier counter reset (per call)
    if (bid < 5120) {
        int i = bid * 256 + threadIdx.x;
        if (i < 524288) {
            cvt4(W1, W1b, i);
        } else if (i < 1048576) {
            cvt4(W2, W2b, i - 524288);
        } else {
            int j = i - 1048576;
            int e = j * 4;
            int row = e >> 10;
            u16x4 o;
            if (row < 1000) {
                f32x4 v = *(const f32x4*)(W3 + e);
                o.x = f2bf(v.x); o.y = f2bf(v.y); o.z = f2bf(v.z); o.w = f2bf(v.w);
            } else {
                o.x = 0; o.y = 0; o.z = 0; o.w = 0;
            }
            *(u16x4*)(W3b + e) = o;
        }
    } else {
        int by = bid - 5120;
        int col = threadIdx.x * 4;
        long base = (long)by * 32 * 1024 + col;
        f32x4 s = {0.f, 0.f, 0.f, 0.f};
        f32x4 q = {0.f, 0.f, 0.f, 0.f};
        for (int r = 0; r < 32; ++r) {
            f32x4 v = *(const f32x4*)(x + base + (long)r * 1024);
            s.x += v.x; s.y += v.y; s.z += v.z; s.w += v.w;
            q.x = fmaf(v.x, v.x, q.x); q.y = fmaf(v.y, v.y, q.y);
            q.z = fmaf(v.z, v.z, q.z); q.w = fmaf(v.w, v.w, q.w);
        }
        long o = ((long)by * 1024 + col) * 2;
        f32x4 p0 = {s.x, q.x, s.y, q.y};
        f32x4 p1 = {s.z, q.z, s.w, q.w};
        *(f32x4*)(part0 + o) = p0;
        *(f32x4*)(part0 + o + 4) = p1;
    }
}

// ---------------- column-stats finalize (nblk partials -> ab) ----------------
__global__ __launch_bounds__(256) void col_stats_finalize(
    const float* __restrict__ part, int cols, int nblk, float inv_n,
    const float* __restrict__ g, const float* __restrict__ b, float* __restrict__ ab) {
    __shared__ float red[8][64];
    int cl = threadIdx.x & 31;
    int j = threadIdx.x >> 5;
    int col = blockIdx.x * 32 + cl;
    int per = nblk / 8;
    float s = 0.f, ss = 0.f;
    for (int i = 0; i < per; ++i) {
        long o = ((long)(j * per + i) * cols + col) * 2;
        s += part[o]; ss += part[o + 1];
    }
    red[j][cl * 2] = s;
    red[j][cl * 2 + 1] = ss;
    __syncthreads();
    if (threadIdx.x < 32) {
        int c = blockIdx.x * 32 + threadIdx.x;
        float fs = 0.f, fss = 0.f;
#pragma unroll
        for (int jj = 0; jj < 8; ++jj) {
            fs += red[jj][threadIdx.x * 2];
            fss += red[jj][threadIdx.x * 2 + 1];
        }
        float m = fs * inv_n;
        float var = fss * inv_n - m * m;
        float a = g[c] * rsqrtf(var + 1e-5f);
        ab[c * 2 + 0] = a;
        ab[c * 2 + 1] = b[c] - m * a;
    }
}

// ---------------- fused BN0-apply + per-channel MM block + STE argmax LUT ----------------
__global__ __launch_bounds__(256) void mm_block_kernel(
    const float* __restrict__ x, const float* __restrict__ ab0,
    const float* __restrict__ S, const float* __restrict__ Tt,
    const float* __restrict__ Hm, const float* __restrict__ LUT,
    u16* __restrict__ v) {
    __shared__ float sS[480];
    __shared__ float sT[60];
    __shared__ float sHm[240];
    __shared__ float sLUT[512];
    __shared__ float sAB[64];
    const int t = threadIdx.x;
    const int cb = blockIdx.y * 4;

    for (int i = t; i < 480; i += 256) sS[i] = S[cb * 120 + i];
    for (int i = t; i < 60; i += 256)  sT[i] = Tt[cb * 15 + i];
    for (int i = t; i < 240; i += 256) sHm[i] = Hm[i];
    for (int i = t; i < 512; i += 256) sLUT[i] = LUT[cb * 128 + i];
    for (int i = t; i < 64; i += 256)  sAB[i] = ab0[cb * 16 + i];
    __syncthreads();

    const int row = blockIdx.x * 256 + t;
    const float* xp = x + (size_t)row * 1024 + cb * 8;
    float xr[32];
#pragma unroll
    for (int i = 0; i < 8; ++i) {
        f32x4 v4 = *(const f32x4*)(xp + i * 4);
        xr[i * 4 + 0] = v4.x; xr[i * 4 + 1] = v4.y;
        xr[i * 4 + 2] = v4.z; xr[i * 4 + 3] = v4.w;
    }
    u16 ov[32];
#pragma unroll
    for (int ch = 0; ch < 4; ++ch) {
        float h[8];
#pragma unroll
        for (int d = 0; d < 8; ++d)
            h[d] = xr[ch * 8 + d] * sAB[ch * 16 + d * 2] + sAB[ch * 16 + d * 2 + 1];
        float lg[16];
#pragma unroll
        for (int j = 0; j < 16; ++j) lg[j] = 0.f;
        for (int k = 0; k < 15; ++k) {
            float a = 0.f;
#pragma unroll
            for (int d = 0; d < 8; ++d) a = fmaf(h[d], sS[ch * 120 + d * 15 + k], a);
            float z = (a - sT[ch * 15 + k]) - 1e-4f;
            float q = (z > 0.f) ? 1.f : ((z < 0.f) ? -1.f : 0.f);
#pragma unroll
            for (int j = 0; j < 16; ++j) lg[j] = fmaf(q, sHm[k * 16 + j], lg[j]);
        }
        int jb = 0; float best = lg[0];
#pragma unroll
        for (int j = 1; j < 16; ++j) { if (lg[j] > best) { best = lg[j]; jb = j; } }
#pragma unroll
        for (int d = 0; d < 8; ++d) ov[ch * 8 + d] = f2bf(sLUT[ch * 128 + jb * 8 + d]);
    }
    u16* vp = v + (size_t)row * 1024 + cb * 8;
#pragma unroll
    for (int ch = 0; ch < 4; ++ch)
        *(u16x8*)(vp + ch * 8) = *(u16x8*)&ov[ch * 8];
}

// ---------------- BN apply + ReLU (x8 vectorized, full occupancy) ----------------
__global__ __launch_bounds__(256) void bn_relu_apply8(
    const u16* __restrict__ y, const float* __restrict__ ab, int cols, int total8,
    float* __restrict__ out_f32, u16* __restrict__ out_b16) {
    int i = blockIdx.x * 256 + threadIdx.x;
    if (i >= total8) return;
    long e = (long)i * 8;
    int col = (int)(e % cols);
    u16x8 yv = *(const u16x8*)(y + e);
    float r[8];
#pragma unroll
    for (int d = 0; d < 8; ++d)
        r[d] = fmaxf(bf2f(yv[d]) * ab[(col + d) * 2] + ab[(col + d) * 2 + 1], 0.f);
    if (out_f32) {
        f32x4 rf0 = {r[0], r[1], r[2], r[3]};
        f32x4 rf1 = {r[4], r[5], r[6], r[7]};
        *(f32x4*)(out_f32 + e) = rf0;
        *(f32x4*)(out_f32 + e + 4) = rf1;
    }
    u16x8 o;
#pragma unroll
    for (int d = 0; d < 8; ++d) o[d] = f2bf(r[d]);
    *(u16x8*)(out_b16 + e) = o;
}

// ---------------- 256x256 deep-pipelined bf16 GEMM, A[M,K] x B[N,K]^T ----------------
// WRITER: last 2 gridDim.y rows are upcast-writer blocks (wsrc bf16 -> wdst f32, NT).
// SMAX: fused log-softmax epilogue (grid must be exactly co-resident: 256 blocks, 1/CU).
#define MFMA16(a, b, c) __builtin_amdgcn_mfma_f32_16x16x32_bf16(a, b, c, 0, 0, 0)

template <bool STORE_BF16, bool DO_STATS, bool WRITER, bool SMAX>
__global__ __launch_bounds__(512, 2) void gemm256(
    const u16* __restrict__ A, const u16* __restrict__ Bm, void* __restrict__ Cv,
    const float* __restrict__ bias, float* __restrict__ part,
    int M, int N, int K, int ldc, int ncol,
    const u16* __restrict__ wsrc, float* __restrict__ wdst, long wn4,
    int* __restrict__ cnt) {
    extern __shared__ u16 lds[];
    const int t = threadIdx.x;
    const int gyG = WRITER ? ((int)gridDim.y - 2) : (int)gridDim.y;  // GEMM rows
    if (WRITER && (int)blockIdx.y >= gyG) {
        long wblk = (long)((int)blockIdx.y - gyG) * gridDim.x + blockIdx.x;  // 0..127
        long tid = wblk * 512 + t;                                           // 0..65535
        for (long c = tid; c < wn4; c += 65536) {
            u16x4 v = *(const u16x4*)(wsrc + c * 4);
            f32x4 o = {bf2f(v.x), bf2f(v.y), bf2f(v.z), bf2f(v.w)};
            __builtin_nontemporal_store(o, (f32x4*)(wdst + c * 4));
        }
        return;
    }
    const int BOFF = 32768;                 // u16 offset of B region (64 KiB)
    const int lane = t & 63, w = t >> 6;
    const int wr = w >> 2, wc = w & 3;
    const int fr = lane & 15, kg = lane >> 4;
    const int gx = gridDim.x;
    const int nwg = gx * gyG;
    const int flat = blockIdx.y * gx + blockIdx.x;
    const int swz = (flat & 7) * (nwg >> 3) + (flat >> 3);
    const int bm = (swz % gx) * 256;
    const int bn = (swz / gx) * 256;
    const int NT = K >> 6;

    const int srow8 = lane >> 3;
    const int scc = (lane & 7) ^ srow8;
    const int L0 = w * 2;
    const u16* gAb = A + ((size_t)bm + L0 * 8 + srow8) * K + scc * 8;
    const u16* gBb = Bm + ((size_t)bn + L0 * 8 + srow8) * K + scc * 8;
    u16* ldsW = lds + L0 * 512 + lane * 8;

    const int s0 = (kg ^ (fr & 7)) * 8;
    const int s1 = s0 ^ 32;
    int rA[4], rB[2];
#pragma unroll
    for (int i = 0; i < 4; ++i) rA[i] = (i * 32 + wr * 16 + fr) * 64;
#pragma unroll
    for (int p = 0; p < 2; ++p) rB[p] = (p * 64 + wc * 16 + fr) * 64;

    f32x4 acc[8][4];
#pragma unroll
    for (int m = 0; m < 8; ++m)
#pragma unroll
        for (int n = 0; n < 4; ++n) acc[m][n] = (f32x4){0.f, 0.f, 0.f, 0.f};

    bf16x8 Ar[8][2], Br[2][2];

#define STG(gp, matOff, d, half, k0)                                          \
    {                                                                         \
        u16* dst_ = ldsW + (matOff) + ((d) * 2 + (half)) * 8192;              \
        const u16* src_ = (gp) + (size_t)((half) * 128) * K + (k0);           \
        gload16(src_, dst_);                                                  \
        gload16(src_ + (size_t)8 * K, dst_ + 512);                            \
    }
#define LDF(off) (*(const bf16x8*)&lds[off])

    STG(gAb, 0, 0, 0, 0);
    STG(gBb, BOFF, 0, 0, 0);
    STG(gAb, 0, 0, 1, 0);
    STG(gBb, BOFF, 0, 1, 0);

#pragma unroll 2
    for (int tt = 0; tt < NT - 1; ++tt) {
        const int d = tt & 1, dn = d ^ 1;
        const int k0n = (tt + 1) << 6;
        const int a0 = (d * 2) * 8192, a1 = (d * 2 + 1) * 8192;
        const int b0 = BOFF + a0, b1 = BOFF + a1;
        WAITV(4); sbar();
        STG(gAb, 0, dn, 0, k0n);
#pragma unroll
        for (int i = 0; i < 4; ++i) { Ar[i][0] = LDF(a0 + rA[i] + s0); Ar[i][1] = LDF(a0 + rA[i] + s1); }
#pragma unroll
        for (int p = 0; p < 2; ++p) { Br[p][0] = LDF(b0 + rB[p] + s0); Br[p][1] = LDF(b0 + rB[p] + s1); }
        __builtin_amdgcn_s_setprio(1);
#pragma unroll
        for (int i = 0; i < 4; ++i)
#pragma unroll
            for (int p = 0; p < 2; ++p) {
                acc[i][p] = MFMA16(Ar[i][0], Br[p][0], acc[i][p]);
                acc[i][p] = MFMA16(Ar[i][1], Br[p][1], acc[i][p]);
            }
        __builtin_amdgcn_s_setprio(0);
        WAITV(4); sbar();
        STG(gBb, BOFF, dn, 0, k0n);
#pragma unroll
        for (int i = 0; i < 4; ++i) { Ar[4 + i][0] = LDF(a1 + rA[i] + s0); Ar[4 + i][1] = LDF(a1 + rA[i] + s1); }
        __builtin_amdgcn_s_setprio(1);
#pragma unroll
        for (int i = 0; i < 4; ++i)
#pragma unroll
            for (int p = 0; p < 2; ++p) {
                acc[4 + i][p] = MFMA16(Ar[4 + i][0], Br[p][0], acc[4 + i][p]);
                acc[4 + i][p] = MFMA16(Ar[4 + i][1], Br[p][1], acc[4 + i][p]);
            }
        __builtin_amdgcn_s_setprio(0);
        WAITV(4); sbar();
        STG(gAb, 0, dn, 1, k0n);
#pragma unroll
        for (int p = 0; p < 2; ++p) { Br[p][0] = LDF(b1 + rB[p] + s0); Br[p][1] = LDF(b1 + rB[p] + s1); }
        __builtin_amdgcn_s_setprio(1);
#pragma unroll
        for (int i = 0; i < 4; ++i)
#pragma unroll
            for (int p = 0; p < 2; ++p) {
                acc[4 + i][2 + p] = MFMA16(Ar[4 + i][0], Br[p][0], acc[4 + i][2 + p]);
                acc[4 + i][2 + p] = MFMA16(Ar[4 + i][1], Br[p][1], acc[4 + i][2 + p]);
            }
        __builtin_amdgcn_s_setprio(0);
        STG(gBb, BOFF, dn, 1, k0n);
        __builtin_amdgcn_s_setprio(1);
#pragma unroll
        for (int i = 0; i < 4; ++i)
#pragma unroll
            for (int p = 0; p < 2; ++p) {
                acc[i][2 + p] = MFMA16(Ar[i][0], Br[p][0], acc[i][2 + p]);
                acc[i][2 + p] = MFMA16(Ar[i][1], Br[p][1], acc[i][2 + p]);
            }
        __builtin_amdgcn_s_setprio(0);
    }
    {
        const int d = (NT - 1) & 1;
        const int a0 = (d * 2) * 8192, a1 = (d * 2 + 1) * 8192;
        const int b0 = BOFF + a0, b1 = BOFF + a1;
        WAITV(4); sbar();
#pragma unroll
        for (int i = 0; i < 4; ++i) { Ar[i][0] = LDF(a0 + rA[i] + s0); Ar[i][1] = LDF(a0 + rA[i] + s1); }
#pragma unroll
        for (int p = 0; p < 2; ++p) { Br[p][0] = LDF(b0 + rB[p] + s0); Br[p][1] = LDF(b0 + rB[p] + s1); }
        __builtin_amdgcn_s_setprio(1);
#pragma unroll
        for (int i = 0; i < 4; ++i)
#pragma unroll
            for (int p = 0; p < 2; ++p) {
                acc[i][p] = MFMA16(Ar[i][0], Br[p][0], acc[i][p]);
                acc[i][p] = MFMA16(Ar[i][1], Br[p][1], acc[i][p]);
            }
        __builtin_amdgcn_s_setprio(0);
        WAITV(2); sbar();
#pragma unroll
        for (int i = 0; i < 4; ++i) { Ar[4 + i][0] = LDF(a1 + rA[i] + s0); Ar[4 + i][1] = LDF(a1 + rA[i] + s1); }
        __builtin_amdgcn_s_setprio(1);
#pragma unroll
        for (int i = 0; i < 4; ++i)
#pragma unroll
            for (int p = 0; p < 2; ++p) {
                acc[4 + i][p] = MFMA16(Ar[4 + i][0], Br[p][0], acc[4 + i][p]);
                acc[4 + i][p] = MFMA16(Ar[4 + i][1], Br[p][1], acc[4 + i][p]);
            }
        __builtin_amdgcn_s_setprio(0);
        WAITV(0); sbar();
#pragma unroll
        for (int p = 0; p < 2; ++p) { Br[p][0] = LDF(b1 + rB[p] + s0); Br[p][1] = LDF(b1 + rB[p] + s1); }
        __builtin_amdgcn_s_setprio(1);
#pragma unroll
        for (int i = 0; i < 4; ++i)
#pragma unroll
            for (int p = 0; p < 2; ++p) {
                acc[4 + i][2 + p] = MFMA16(Ar[4 + i][0], Br[p][0], acc[4 + i][2 + p]);
                acc[4 + i][2 + p] = MFMA16(Ar[4 + i][1], Br[p][1], acc[4 + i][2 + p]);
                acc[i][2 + p] = MFMA16(Ar[i][0], Br[p][0], acc[i][2 + p]);
                acc[i][2 + p] = MFMA16(Ar[i][1], Br[p][1], acc[i][2 + p]);
            }
        __builtin_amdgcn_s_setprio(0);
    }

    const int fq = lane >> 4;
    if (STORE_BF16) {
        // coalesced C-write: per 32-row group, transpose through LDS, store u16x8 rows
        u16* C = (u16*)Cv;
        u16* sm = lds;                       // [32][256] u16 = 16 KiB (dbuf LDS is dead)
        const int orow = t >> 4;             // 0..31
        const int ocol = (t & 15) * 16;      // 0..240
#pragma unroll
        for (int m = 0; m < 8; ++m) {
            __syncthreads();
#pragma unroll
            for (int n = 0; n < 4; ++n)
#pragma unroll
                for (int j = 0; j < 4; ++j)
                    sm[(wr * 16 + fq * 4 + j) * 256 + n * 64 + wc * 16 + fr] = f2bf(acc[m][n][j]);
            __syncthreads();
            u16x8 o0 = *(const u16x8*)&sm[orow * 256 + ocol];
            u16x8 o1 = *(const u16x8*)&sm[orow * 256 + ocol + 8];
            u16* cp = C + (size_t)(bm + m * 32 + orow) * ldc + bn + ocol;
            *(u16x8*)cp = o0;
            *(u16x8*)(cp + 8) = o1;
        }
    } else if (SMAX) {
        // ---- fused log-softmax epilogue (grid = exactly-co-resident 256 blocks) ----
        float* out = (float*)Cv;
        float* smf = (float*)lds;            // [4 wc][256 rows][2] = 8 KiB
        float bv[4]; bool vld[4]; int cc[4];
#pragma unroll
        for (int n = 0; n < 4; ++n) {
            cc[n] = bn + n * 64 + wc * 16 + fr;
            vld[n] = cc[n] < ncol;
            bv[n] = vld[n] ? bias[cc[n]] : 0.f;
        }
#pragma unroll
        for (int m = 0; m < 8; ++m)
#pragma unroll
            for (int n = 0; n < 4; ++n)
#pragma unroll
                for (int j = 0; j < 4; ++j) acc[m][n][j] += bv[n];
        __syncthreads();
        // per-row slice stats: max + sumexp over this block's 256-col slice
#pragma unroll
        for (int m = 0; m < 8; ++m) {
#pragma unroll
            for (int j = 0; j < 4; ++j) {
                float mx = -1e30f;
#pragma unroll
                for (int n = 0; n < 4; ++n) if (vld[n]) mx = fmaxf(mx, acc[m][n][j]);
                mx = fmaxf(mx, __shfl_xor(mx, 1));
                mx = fmaxf(mx, __shfl_xor(mx, 2));
                mx = fmaxf(mx, __shfl_xor(mx, 4));
                mx = fmaxf(mx, __shfl_xor(mx, 8));
                float se = 0.f;
#pragma unroll
                for (int n = 0; n < 4; ++n) if (vld[n]) se += expf(acc[m][n][j] - mx);
                se += __shfl_xor(se, 1);
                se += __shfl_xor(se, 2);
                se += __shfl_xor(se, 4);
                se += __shfl_xor(se, 8);
                if (fr == 0) {
                    int rl = m * 32 + wr * 16 + kg * 4 + j;
                    smf[(wc * 256 + rl) * 2] = mx;
                    smf[(wc * 256 + rl) * 2 + 1] = se;
                }
            }
        }
        __syncthreads();
        if (t < 256) {   // combine the 4 wave-slices, write per-(slice,row) partials
            float m0 = smf[(0 * 256 + t) * 2], sA = smf[(0 * 256 + t) * 2 + 1];
            float m1 = smf[(1 * 256 + t) * 2], sB = smf[(1 * 256 + t) * 2 + 1];
            float m2 = smf[(2 * 256 + t) * 2], sC = smf[(2 * 256 + t) * 2 + 1];
            float m3 = smf[(3 * 256 + t) * 2], sD = smf[(3 * 256 + t) * 2 + 1];
            float Mm = fmaxf(fmaxf(m0, m1), fmaxf(m2, m3));
            float Ss = sA * expf(m0 - Mm) + sB * expf(m1 - Mm)
                     + sC * expf(m2 - Mm) + sD * expf(m3 - Mm);
            long o = ((long)(bn >> 8) * M + bm + t) * 2;
            part[o] = Mm;
            part[o + 1] = Ss;
        }
        // ---- device-scope grid barrier (all 256 blocks co-resident: 128KiB LDS -> 1/CU) ----
        __syncthreads();
        if (t == 0) {
            __threadfence();                       // wbL2: flush this block's partial stores
            atomicAdd(cnt, 1);
            while (atomicAdd(cnt, 0) < nwg) {}     // device-scope RMW spin
            __threadfence();                       // invalidate caches before partial reads
        }
        __syncthreads();
        if (t < 256) {   // per-row LSE from the 4 column slices
            int row = bm + t;
            float m0 = part[((long)0 * M + row) * 2], sA = part[((long)0 * M + row) * 2 + 1];
            float m1 = part[((long)1 * M + row) * 2], sB = part[((long)1 * M + row) * 2 + 1];
            float m2 = part[((long)2 * M + row) * 2], sC = part[((long)2 * M + row) * 2 + 1];
            float m3 = part[((long)3 * M + row) * 2], sD = part[((long)3 * M + row) * 2 + 1];
            float Mm = fmaxf(fmaxf(m0, m1), fmaxf(m2, m3));
            float Ss = sA * expf(m0 - Mm) + sB * expf(m1 - Mm)
                     + sC * expf(m2 - Mm) + sD * expf(m3 - Mm);
            smf[t] = Mm + logf(Ss);
        }
        __syncthreads();
#pragma unroll
        for (int m = 0; m < 8; ++m) {
#pragma unroll
            for (int j = 0; j < 4; ++j) {
                int rl = m * 32 + wr * 16 + fq * 4 + j;
                float lse = smf[rl];
#pragma unroll
                for (int n = 0; n < 4; ++n)
                    if (vld[n])
                        __builtin_nontemporal_store(acc[m][n][j] - lse,
                            &out[(size_t)(bm + rl) * ldc + cc[n]]);
            }
        }
    } else {
#pragma unroll
        for (int m = 0; m < 8; ++m) {
#pragma unroll
            for (int n = 0; n < 4; ++n) {
                int row = bm + m * 32 + wr * 16 + fq * 4;
                int col = bn + n * 64 + wc * 16 + fr;
                if (col < ncol) {
                    float* C = (float*)Cv;
                    float bvv = bias ? bias[col] : 0.f;
#pragma unroll
                    for (int j = 0; j < 4; ++j)
                        C[(size_t)(row + j) * ldc + col] = acc[m][n][j] + bvv;
                }
            }
        }
    }

    if (DO_STATS) {
        __syncthreads();
        float* smf = (float*)lds;   // [8 waves][64 cols][2]
        float sv[4], qv[4];
#pragma unroll
        for (int n = 0; n < 4; ++n) {
            float s = 0.f, q = 0.f;
#pragma unroll
            for (int m = 0; m < 8; ++m)
#pragma unroll
                for (int j = 0; j < 4; ++j) {
                    float vv = acc[m][n][j];
                    s += vv;
                    q = fmaf(vv, vv, q);
                }
            s += __shfl_xor(s, 16); s += __shfl_xor(s, 32);
            q += __shfl_xor(q, 16); q += __shfl_xor(q, 32);
            sv[n] = s; qv[n] = q;
        }
        if (lane < 16) {
#pragma unroll
            for (int n = 0; n < 4; ++n) {
                smf[(w * 64 + n * 16 + lane) * 2 + 0] = sv[n];
                smf[(w * 64 + n * 16 + lane) * 2 + 1] = qv[n];
            }
        }
        __syncthreads();
        if (t < 256) {
            int n = t >> 6, wcq = (t >> 4) & 3, frq = t & 15;
            int i0 = (wcq * 64 + n * 16 + frq) * 2;
            int i1 = ((4 + wcq) * 64 + n * 16 + frq) * 2;
            long o = ((long)(bm >> 8) * N + bn + t) * 2;
            part[o] = smf[i0] + smf[i1];
            part[o + 1] = smf[i0 + 1] + smf[i1 + 1];
        }
    }
#undef STG
#undef LDF
}

extern "C" void kernel_launch(void* const* d_in, const int* in_sizes, int n_in,
                              void* d_out, int out_size, void* d_ws, size_t ws_size,
                              hipStream_t stream) {
    const float* x   = (const float*)d_in[0];
    const float* n0g = (const float*)d_in[1];
    const float* n0b = (const float*)d_in[2];
    const float* S   = (const float*)d_in[3];
    const float* Hm  = (const float*)d_in[4];
    const float* Tt  = (const float*)d_in[5];
    const float* LUT = (const float*)d_in[6];
    const float* W1  = (const float*)d_in[7];
    const float* n1g = (const float*)d_in[9];
    const float* n1b = (const float*)d_in[10];
    const float* W2  = (const float*)d_in[11];
    const float* n2g = (const float*)d_in[13];
    const float* n2b = (const float*)d_in[14];
    const float* W3  = (const float*)d_in[15];
    const float* b3  = (const float*)d_in[16];

    const int B = 16384, IN = 1024, H1 = 2048, H2 = 1024;
    const int NBY0 = 512;

    hipFuncSetAttribute((const void*)&gemm256<true, true, false, false>,
                        hipFuncAttributeMaxDynamicSharedMemorySize, 131072);
    hipFuncSetAttribute((const void*)&gemm256<true, true, true, false>,
                        hipFuncAttributeMaxDynamicSharedMemorySize, 131072);
    hipFuncSetAttribute((const void*)&gemm256<false, false, false, true>,
                        hipFuncAttributeMaxDynamicSharedMemorySize, 131072);

    char* ws = (char*)d_ws;
    size_t off = 0;
    auto alloc = [&](size_t bytes) -> char* {
        char* p = ws + off;
        off += (bytes + 255) & ~(size_t)255;
        return p;
    };
    int*   cnt  = (int*)alloc(256);
    float* ab0  = (float*)alloc(IN * 2 * sizeof(float));
    float* ab1  = (float*)alloc(H1 * 2 * sizeof(float));
    float* ab2  = (float*)alloc(H2 * 2 * sizeof(float));
    float* part0 = (float*)alloc((size_t)NBY0 * IN * 2 * sizeof(float));
    float* part1 = (float*)alloc((size_t)(B / 256) * H1 * 2 * sizeof(float));
    float* part2 = (float*)alloc((size_t)(B / 256) * H2 * 2 * sizeof(float));
    float* part3 = (float*)alloc((size_t)4 * B * 2 * sizeof(float));   // softmax slice stats
    u16* W1b = (u16*)alloc((size_t)H1 * IN * 2);
    u16* W2b = (u16*)alloc((size_t)H2 * H1 * 2);
    u16* W3b = (u16*)alloc((size_t)1024 * 1024 * 2);
    u16* vb  = (u16*)alloc((size_t)B * IN * 2);        // v, later y2/h2
    u16* y1b = (u16*)alloc((size_t)B * H1 * 2);        // y1, then h1 (in-place)

    float* out0 = (float*)d_out;                        // [16384,1000]
    float* out1 = out0 + (size_t)B * 1000;              // [16384,2048] h1 f32

    // 1: weight cvt + BN0 partial stats (merged leaves) + barrier-counter reset
    leaf_kernel<<<5120 + NBY0, 256, 0, stream>>>(W1, W2, W3, W1b, W2b, W3b, x, part0, cnt);

    // 2: BN0 finalize
    col_stats_finalize<<<IN / 32, 256, 0, stream>>>(part0, IN, NBY0, 1.f / B, n0g, n0b, ab0);

    // 3: fused BN0-apply + MM block -> v (bf16)
    mm_block_kernel<<<dim3(B / 256, 32), 256, 0, stream>>>(x, ab0, S, Tt, Hm, LUT, vb);

    // 4: GEMM1 (+BN1 stats): v[B,1024] x W1[2048,1024]^T -> y1 bf16
    gemm256<true, true, false, false><<<dim3(B / 256, H1 / 256), 512, 131072, stream>>>(
        vb, W1b, y1b, nullptr, part1, B, H1, IN, H1, H1, nullptr, nullptr, 0, nullptr);

    // 5-6: BN1 finalize + apply (+ReLU), h1 bf16 in-place only (f32 out1 deferred)
    col_stats_finalize<<<H1 / 32, 256, 0, stream>>>(part1, H1, B / 256, 1.f / B, n1g, n1b, ab1);
    bn_relu_apply8<<<B * H1 / 8 / 256, 256, 0, stream>>>(y1b, ab1, H1, B * H1 / 8, nullptr, y1b);

    // 7: GEMM2 (+BN2 stats), grid y = 4 GEMM rows + 2 writer rows (h1 bf16 -> f32 out1, NT)
    gemm256<true, true, true, false><<<dim3(B / 256, H2 / 256 + 2), 512, 131072, stream>>>(
        y1b, W2b, vb, nullptr, part2, B, H2, H1, H2, H2,
        y1b, out1, (long)B * H1 / 4, nullptr);

    // 8-9: BN2 finalize + apply (+ReLU), bf16 in-place
    col_stats_finalize<<<H2 / 32, 256, 0, stream>>>(part2, H2, B / 256, 1.f / B, n2g, n2b, ab2);
    bn_relu_apply8<<<B * H2 / 8 / 256, 256, 0, stream>>>(vb, ab2, H2, B * H2 / 8, nullptr, vb);

    // 10: GEMM3 + fused log-softmax (grid barrier; 256 blocks co-resident at 1/CU)
    gemm256<false, false, false, true><<<dim3(B / 256, 1024 / 256), 512, 131072, stream>>>(
        vb, W3b, out0, b3, part3, B, 1024, H2, 1000, 1000, nullptr, nullptr, 0, cnt);
}

// Round 11
// 356.281 us; speedup vs baseline: 1.0928x; 1.0928x over previous
//
#include <hip/hip_runtime.h>

typedef unsigned short u16;
typedef __attribute__((ext_vector_type(8))) short bf16x8;
typedef __attribute__((ext_vector_type(4))) float f32x4;
typedef __attribute__((ext_vector_type(4))) u16 u16x4;
typedef __attribute__((ext_vector_type(8))) u16 u16x8;

__device__ __forceinline__ u16 f2bf(float f) {
    union { float f; unsigned u; } v; v.f = f;
    unsigned u = v.u;
    unsigned r = (u + 0x7fffu + ((u >> 16) & 1u)) >> 16;
    return (u16)r;
}
__device__ __forceinline__ float bf2f(u16 u) {
    union { unsigned u; float f; } v; v.u = ((unsigned)u) << 16;
    return v.f;
}

__device__ __forceinline__ void gload16(const u16* g, u16* l) {
    __builtin_amdgcn_global_load_lds((const __attribute__((address_space(1))) void*)g,
                                     (__attribute__((address_space(3))) void*)l, 16, 0, 0);
}

#define WAITV(N) asm volatile("s_waitcnt vmcnt(" #N ")" ::: "memory")

__device__ __forceinline__ void sbar() {
    __builtin_amdgcn_sched_barrier(0);
    __builtin_amdgcn_s_barrier();
    __builtin_amdgcn_sched_barrier(0);
}

// ---------------- merged leaves: weight cvt (blocks 0..5119) + BN0 partial stats ----------------
__device__ __forceinline__ void cvt4(const float* in, u16* out, int i) {
    f32x4 v = *(const f32x4*)(in + (size_t)i * 4);
    u16x4 o;
    o.x = f2bf(v.x); o.y = f2bf(v.y); o.z = f2bf(v.z); o.w = f2bf(v.w);
    *(u16x4*)(out + (size_t)i * 4) = o;
}

__global__ __launch_bounds__(256) void leaf_kernel(
    const float* __restrict__ W1, const float* __restrict__ W2, const float* __restrict__ W3,
    u16* __restrict__ W1b, u16* __restrict__ W2b, u16* __restrict__ W3b,
    const float* __restrict__ x, float* __restrict__ part0) {
    int bid = blockIdx.x;
    if (bid < 5120) {
        int i = bid * 256 + threadIdx.x;
        if (i < 524288) {
            cvt4(W1, W1b, i);
        } else if (i < 1048576) {
            cvt4(W2, W2b, i - 524288);
        } else {
            int j = i - 1048576;
            int e = j * 4;
            int row = e >> 10;
            u16x4 o;
            if (row < 1000) {
                f32x4 v = *(const f32x4*)(W3 + e);
                o.x = f2bf(v.x); o.y = f2bf(v.y); o.z = f2bf(v.z); o.w = f2bf(v.w);
            } else {
                o.x = 0; o.y = 0; o.z = 0; o.w = 0;
            }
            *(u16x4*)(W3b + e) = o;
        }
    } else {
        int by = bid - 5120;
        int col = threadIdx.x * 4;
        long base = (long)by * 32 * 1024 + col;
        f32x4 s = {0.f, 0.f, 0.f, 0.f};
        f32x4 q = {0.f, 0.f, 0.f, 0.f};
        for (int r = 0; r < 32; ++r) {
            f32x4 v = *(const f32x4*)(x + base + (long)r * 1024);
            s.x += v.x; s.y += v.y; s.z += v.z; s.w += v.w;
            q.x = fmaf(v.x, v.x, q.x); q.y = fmaf(v.y, v.y, q.y);
            q.z = fmaf(v.z, v.z, q.z); q.w = fmaf(v.w, v.w, q.w);
        }
        long o = ((long)by * 1024 + col) * 2;
        f32x4 p0 = {s.x, q.x, s.y, q.y};
        f32x4 p1 = {s.z, q.z, s.w, q.w};
        *(f32x4*)(part0 + o) = p0;
        *(f32x4*)(part0 + o + 4) = p1;
    }
}

// ---------------- column-stats finalize (nblk partials -> ab) ----------------
__global__ __launch_bounds__(256) void col_stats_finalize(
    const float* __restrict__ part, int cols, int nblk, float inv_n,
    const float* __restrict__ g, const float* __restrict__ b, float* __restrict__ ab) {
    __shared__ float red[8][64];
    int cl = threadIdx.x & 31;
    int j = threadIdx.x >> 5;
    int col = blockIdx.x * 32 + cl;
    int per = nblk / 8;
    float s = 0.f, ss = 0.f;
    for (int i = 0; i < per; ++i) {
        long o = ((long)(j * per + i) * cols + col) * 2;
        s += part[o]; ss += part[o + 1];
    }
    red[j][cl * 2] = s;
    red[j][cl * 2 + 1] = ss;
    __syncthreads();
    if (threadIdx.x < 32) {
        int c = blockIdx.x * 32 + threadIdx.x;
        float fs = 0.f, fss = 0.f;
#pragma unroll
        for (int jj = 0; jj < 8; ++jj) {
            fs += red[jj][threadIdx.x * 2];
            fss += red[jj][threadIdx.x * 2 + 1];
        }
        float m = fs * inv_n;
        float var = fss * inv_n - m * m;
        float a = g[c] * rsqrtf(var + 1e-5f);
        ab[c * 2 + 0] = a;
        ab[c * 2 + 1] = b[c] - m * a;
    }
}

// ---------------- fused BN0-apply + per-channel MM block + STE argmax LUT ----------------
__global__ __launch_bounds__(256) void mm_block_kernel(
    const float* __restrict__ x, const float* __restrict__ ab0,
    const float* __restrict__ S, const float* __restrict__ Tt,
    const float* __restrict__ Hm, const float* __restrict__ LUT,
    u16* __restrict__ v) {
    __shared__ float sS[480];
    __shared__ float sT[60];
    __shared__ float sHm[240];
    __shared__ float sLUT[512];
    __shared__ float sAB[64];
    const int t = threadIdx.x;
    const int cb = blockIdx.y * 4;

    for (int i = t; i < 480; i += 256) sS[i] = S[cb * 120 + i];
    for (int i = t; i < 60; i += 256)  sT[i] = Tt[cb * 15 + i];
    for (int i = t; i < 240; i += 256) sHm[i] = Hm[i];
    for (int i = t; i < 512; i += 256) sLUT[i] = LUT[cb * 128 + i];
    for (int i = t; i < 64; i += 256)  sAB[i] = ab0[cb * 16 + i];
    __syncthreads();

    const int row = blockIdx.x * 256 + t;
    const float* xp = x + (size_t)row * 1024 + cb * 8;
    float xr[32];
#pragma unroll
    for (int i = 0; i < 8; ++i) {
        f32x4 v4 = *(const f32x4*)(xp + i * 4);
        xr[i * 4 + 0] = v4.x; xr[i * 4 + 1] = v4.y;
        xr[i * 4 + 2] = v4.z; xr[i * 4 + 3] = v4.w;
    }
    u16 ov[32];
#pragma unroll
    for (int ch = 0; ch < 4; ++ch) {
        float h[8];
#pragma unroll
        for (int d = 0; d < 8; ++d)
            h[d] = xr[ch * 8 + d] * sAB[ch * 16 + d * 2] + sAB[ch * 16 + d * 2 + 1];
        float lg[16];
#pragma unroll
        for (int j = 0; j < 16; ++j) lg[j] = 0.f;
        for (int k = 0; k < 15; ++k) {
            float a = 0.f;
#pragma unroll
            for (int d = 0; d < 8; ++d) a = fmaf(h[d], sS[ch * 120 + d * 15 + k], a);
            float z = (a - sT[ch * 15 + k]) - 1e-4f;
            float q = (z > 0.f) ? 1.f : ((z < 0.f) ? -1.f : 0.f);
#pragma unroll
            for (int j = 0; j < 16; ++j) lg[j] = fmaf(q, sHm[k * 16 + j], lg[j]);
        }
        int jb = 0; float best = lg[0];
#pragma unroll
        for (int j = 1; j < 16; ++j) { if (lg[j] > best) { best = lg[j]; jb = j; } }
#pragma unroll
        for (int d = 0; d < 8; ++d) ov[ch * 8 + d] = f2bf(sLUT[ch * 128 + jb * 8 + d]);
    }
    u16* vp = v + (size_t)row * 1024 + cb * 8;
#pragma unroll
    for (int ch = 0; ch < 4; ++ch)
        *(u16x8*)(vp + ch * 8) = *(u16x8*)&ov[ch * 8];
}

// ---------------- BN apply + ReLU (x8 vectorized, full occupancy) ----------------
__global__ __launch_bounds__(256) void bn_relu_apply8(
    const u16* __restrict__ y, const float* __restrict__ ab, int cols, int total8,
    float* __restrict__ out_f32, u16* __restrict__ out_b16) {
    int i = blockIdx.x * 256 + threadIdx.x;
    if (i >= total8) return;
    long e = (long)i * 8;
    int col = (int)(e % cols);
    u16x8 yv = *(const u16x8*)(y + e);
    float r[8];
#pragma unroll
    for (int d = 0; d < 8; ++d)
        r[d] = fmaxf(bf2f(yv[d]) * ab[(col + d) * 2] + ab[(col + d) * 2 + 1], 0.f);
    if (out_f32) {
        f32x4 rf0 = {r[0], r[1], r[2], r[3]};
        f32x4 rf1 = {r[4], r[5], r[6], r[7]};
        *(f32x4*)(out_f32 + e) = rf0;
        *(f32x4*)(out_f32 + e + 4) = rf1;
    }
    u16x8 o;
#pragma unroll
    for (int d = 0; d < 8; ++d) o[d] = f2bf(r[d]);
    *(u16x8*)(out_b16 + e) = o;
}

// ---------------- 256x256 deep-pipelined bf16 GEMM, A[M,K] x B[N,K]^T ----------------
// WRITER: last 2 gridDim.y rows are upcast-writer blocks (wsrc bf16 -> wdst f32, NT).
#define MFMA16(a, b, c) __builtin_amdgcn_mfma_f32_16x16x32_bf16(a, b, c, 0, 0, 0)

template <bool STORE_BF16, bool DO_STATS, bool WRITER>
__global__ __launch_bounds__(512, 2) void gemm256(
    const u16* __restrict__ A, const u16* __restrict__ Bm, void* __restrict__ Cv,
    const float* __restrict__ bias, float* __restrict__ part,
    int M, int N, int K, int ldc, int ncol,
    const u16* __restrict__ wsrc, float* __restrict__ wdst, long wn4) {
    extern __shared__ u16 lds[];
    const int t = threadIdx.x;
    const int gyG = WRITER ? ((int)gridDim.y - 2) : (int)gridDim.y;  // GEMM rows
    if (WRITER && (int)blockIdx.y >= gyG) {
        long wblk = (long)((int)blockIdx.y - gyG) * gridDim.x + blockIdx.x;  // 0..127
        long tid = wblk * 512 + t;                                           // 0..65535
        for (long c = tid; c < wn4; c += 65536) {
            u16x4 v = *(const u16x4*)(wsrc + c * 4);
            f32x4 o = {bf2f(v.x), bf2f(v.y), bf2f(v.z), bf2f(v.w)};
            __builtin_nontemporal_store(o, (f32x4*)(wdst + c * 4));
        }
        return;
    }
    const int BOFF = 32768;                 // u16 offset of B region (64 KiB)
    const int lane = t & 63, w = t >> 6;
    const int wr = w >> 2, wc = w & 3;
    const int fr = lane & 15, kg = lane >> 4;
    const int gx = gridDim.x;
    const int nwg = gx * gyG;
    const int flat = blockIdx.y * gx + blockIdx.x;
    const int swz = (flat & 7) * (nwg >> 3) + (flat >> 3);
    const int bm = (swz % gx) * 256;
    const int bn = (swz / gx) * 256;
    const int NT = K >> 6;

    const int srow8 = lane >> 3;
    const int scc = (lane & 7) ^ srow8;
    const int L0 = w * 2;
    const u16* gAb = A + ((size_t)bm + L0 * 8 + srow8) * K + scc * 8;
    const u16* gBb = Bm + ((size_t)bn + L0 * 8 + srow8) * K + scc * 8;
    u16* ldsW = lds + L0 * 512 + lane * 8;

    const int s0 = (kg ^ (fr & 7)) * 8;
    const int s1 = s0 ^ 32;
    int rA[4], rB[2];
#pragma unroll
    for (int i = 0; i < 4; ++i) rA[i] = (i * 32 + wr * 16 + fr) * 64;
#pragma unroll
    for (int p = 0; p < 2; ++p) rB[p] = (p * 64 + wc * 16 + fr) * 64;

    f32x4 acc[8][4];
#pragma unroll
    for (int m = 0; m < 8; ++m)
#pragma unroll
        for (int n = 0; n < 4; ++n) acc[m][n] = (f32x4){0.f, 0.f, 0.f, 0.f};

    bf16x8 Ar[8][2], Br[2][2];

#define STG(gp, matOff, d, half, k0)                                          \
    {                                                                         \
        u16* dst_ = ldsW + (matOff) + ((d) * 2 + (half)) * 8192;              \
        const u16* src_ = (gp) + (size_t)((half) * 128) * K + (k0);           \
        gload16(src_, dst_);                                                  \
        gload16(src_ + (size_t)8 * K, dst_ + 512);                            \
    }
#define LDF(off) (*(const bf16x8*)&lds[off])

    STG(gAb, 0, 0, 0, 0);
    STG(gBb, BOFF, 0, 0, 0);
    STG(gAb, 0, 0, 1, 0);
    STG(gBb, BOFF, 0, 1, 0);

#pragma unroll 2
    for (int tt = 0; tt < NT - 1; ++tt) {
        const int d = tt & 1, dn = d ^ 1;
        const int k0n = (tt + 1) << 6;
        const int a0 = (d * 2) * 8192, a1 = (d * 2 + 1) * 8192;
        const int b0 = BOFF + a0, b1 = BOFF + a1;
        WAITV(4); sbar();
        STG(gAb, 0, dn, 0, k0n);
#pragma unroll
        for (int i = 0; i < 4; ++i) { Ar[i][0] = LDF(a0 + rA[i] + s0); Ar[i][1] = LDF(a0 + rA[i] + s1); }
#pragma unroll
        for (int p = 0; p < 2; ++p) { Br[p][0] = LDF(b0 + rB[p] + s0); Br[p][1] = LDF(b0 + rB[p] + s1); }
        __builtin_amdgcn_s_setprio(1);
#pragma unroll
        for (int i = 0; i < 4; ++i)
#pragma unroll
            for (int p = 0; p < 2; ++p) {
                acc[i][p] = MFMA16(Ar[i][0], Br[p][0], acc[i][p]);
                acc[i][p] = MFMA16(Ar[i][1], Br[p][1], acc[i][p]);
            }
        __builtin_amdgcn_s_setprio(0);
        WAITV(4); sbar();
        STG(gBb, BOFF, dn, 0, k0n);
#pragma unroll
        for (int i = 0; i < 4; ++i) { Ar[4 + i][0] = LDF(a1 + rA[i] + s0); Ar[4 + i][1] = LDF(a1 + rA[i] + s1); }
        __builtin_amdgcn_s_setprio(1);
#pragma unroll
        for (int i = 0; i < 4; ++i)
#pragma unroll
            for (int p = 0; p < 2; ++p) {
                acc[4 + i][p] = MFMA16(Ar[4 + i][0], Br[p][0], acc[4 + i][p]);
                acc[4 + i][p] = MFMA16(Ar[4 + i][1], Br[p][1], acc[4 + i][p]);
            }
        __builtin_amdgcn_s_setprio(0);
        WAITV(4); sbar();
        STG(gAb, 0, dn, 1, k0n);
#pragma unroll
        for (int p = 0; p < 2; ++p) { Br[p][0] = LDF(b1 + rB[p] + s0); Br[p][1] = LDF(b1 + rB[p] + s1); }
        __builtin_amdgcn_s_setprio(1);
#pragma unroll
        for (int i = 0; i < 4; ++i)
#pragma unroll
            for (int p = 0; p < 2; ++p) {
                acc[4 + i][2 + p] = MFMA16(Ar[4 + i][0], Br[p][0], acc[4 + i][2 + p]);
                acc[4 + i][2 + p] = MFMA16(Ar[4 + i][1], Br[p][1], acc[4 + i][2 + p]);
            }
        __builtin_amdgcn_s_setprio(0);
        STG(gBb, BOFF, dn, 1, k0n);
        __builtin_amdgcn_s_setprio(1);
#pragma unroll
        for (int i = 0; i < 4; ++i)
#pragma unroll
            for (int p = 0; p < 2; ++p) {
                acc[i][2 + p] = MFMA16(Ar[i][0], Br[p][0], acc[i][2 + p]);
                acc[i][2 + p] = MFMA16(Ar[i][1], Br[p][1], acc[i][2 + p]);
            }
        __builtin_amdgcn_s_setprio(0);
    }
    {
        const int d = (NT - 1) & 1;
        const int a0 = (d * 2) * 8192, a1 = (d * 2 + 1) * 8192;
        const int b0 = BOFF + a0, b1 = BOFF + a1;
        WAITV(4); sbar();
#pragma unroll
        for (int i = 0; i < 4; ++i) { Ar[i][0] = LDF(a0 + rA[i] + s0); Ar[i][1] = LDF(a0 + rA[i] + s1); }
#pragma unroll
        for (int p = 0; p < 2; ++p) { Br[p][0] = LDF(b0 + rB[p] + s0); Br[p][1] = LDF(b0 + rB[p] + s1); }
        __builtin_amdgcn_s_setprio(1);
#pragma unroll
        for (int i = 0; i < 4; ++i)
#pragma unroll
            for (int p = 0; p < 2; ++p) {
                acc[i][p] = MFMA16(Ar[i][0], Br[p][0], acc[i][p]);
                acc[i][p] = MFMA16(Ar[i][1], Br[p][1], acc[i][p]);
            }
        __builtin_amdgcn_s_setprio(0);
        WAITV(2); sbar();
#pragma unroll
        for (int i = 0; i < 4; ++i) { Ar[4 + i][0] = LDF(a1 + rA[i] + s0); Ar[4 + i][1] = LDF(a1 + rA[i] + s1); }
        __builtin_amdgcn_s_setprio(1);
#pragma unroll
        for (int i = 0; i < 4; ++i)
#pragma unroll
            for (int p = 0; p < 2; ++p) {
                acc[4 + i][p] = MFMA16(Ar[4 + i][0], Br[p][0], acc[4 + i][p]);
                acc[4 + i][p] = MFMA16(Ar[4 + i][1], Br[p][1], acc[4 + i][p]);
            }
        __builtin_amdgcn_s_setprio(0);
        WAITV(0); sbar();
#pragma unroll
        for (int p = 0; p < 2; ++p) { Br[p][0] = LDF(b1 + rB[p] + s0); Br[p][1] = LDF(b1 + rB[p] + s1); }
        __builtin_amdgcn_s_setprio(1);
#pragma unroll
        for (int i = 0; i < 4; ++i)
#pragma unroll
            for (int p = 0; p < 2; ++p) {
                acc[4 + i][2 + p] = MFMA16(Ar[4 + i][0], Br[p][0], acc[4 + i][2 + p]);
                acc[4 + i][2 + p] = MFMA16(Ar[4 + i][1], Br[p][1], acc[4 + i][2 + p]);
                acc[i][2 + p] = MFMA16(Ar[i][0], Br[p][0], acc[i][2 + p]);
                acc[i][2 + p] = MFMA16(Ar[i][1], Br[p][1], acc[i][2 + p]);
            }
        __builtin_amdgcn_s_setprio(0);
    }

    const int fq = lane >> 4;
    if (STORE_BF16) {
        // coalesced C-write: per 32-row group, transpose through LDS, store u16x8 rows
        u16* C = (u16*)Cv;
        u16* sm = lds;                       // [32][256] u16 = 16 KiB (dbuf LDS is dead)
        const int orow = t >> 4;             // 0..31
        const int ocol = (t & 15) * 16;      // 0..240
#pragma unroll
        for (int m = 0; m < 8; ++m) {
            __syncthreads();
#pragma unroll
            for (int n = 0; n < 4; ++n)
#pragma unroll
                for (int j = 0; j < 4; ++j)
                    sm[(wr * 16 + fq * 4 + j) * 256 + n * 64 + wc * 16 + fr] = f2bf(acc[m][n][j]);
            __syncthreads();
            u16x8 o0 = *(const u16x8*)&sm[orow * 256 + ocol];
            u16x8 o1 = *(const u16x8*)&sm[orow * 256 + ocol + 8];
            u16* cp = C + (size_t)(bm + m * 32 + orow) * ldc + bn + ocol;
            *(u16x8*)cp = o0;
            *(u16x8*)(cp + 8) = o1;
        }
    } else {
#pragma unroll
        for (int m = 0; m < 8; ++m) {
#pragma unroll
            for (int n = 0; n < 4; ++n) {
                int row = bm + m * 32 + wr * 16 + fq * 4;
                int col = bn + n * 64 + wc * 16 + fr;
                if (col < ncol) {
                    float* C = (float*)Cv;
                    float bv = bias ? bias[col] : 0.f;
#pragma unroll
                    for (int j = 0; j < 4; ++j)
                        C[(size_t)(row + j) * ldc + col] = acc[m][n][j] + bv;
                }
            }
        }
    }

    if (DO_STATS) {
        __syncthreads();
        float* smf = (float*)lds;   // [8 waves][64 cols][2]
        float sv[4], qv[4];
#pragma unroll
        for (int n = 0; n < 4; ++n) {
            float s = 0.f, q = 0.f;
#pragma unroll
            for (int m = 0; m < 8; ++m)
#pragma unroll
                for (int j = 0; j < 4; ++j) {
                    float vv = acc[m][n][j];
                    s += vv;
                    q = fmaf(vv, vv, q);
                }
            s += __shfl_xor(s, 16); s += __shfl_xor(s, 32);
            q += __shfl_xor(q, 16); q += __shfl_xor(q, 32);
            sv[n] = s; qv[n] = q;
        }
        if (lane < 16) {
#pragma unroll
            for (int n = 0; n < 4; ++n) {
                smf[(w * 64 + n * 16 + lane) * 2 + 0] = sv[n];
                smf[(w * 64 + n * 16 + lane) * 2 + 1] = qv[n];
            }
        }
        __syncthreads();
        if (t < 256) {
            int n = t >> 6, wcq = (t >> 4) & 3, frq = t & 15;
            int i0 = (wcq * 64 + n * 16 + frq) * 2;
            int i1 = ((4 + wcq) * 64 + n * 16 + frq) * 2;
            long o = ((long)(bm >> 8) * N + bn + t) * 2;
            part[o] = smf[i0] + smf[i1];
            part[o + 1] = smf[i0 + 1] + smf[i1 + 1];
        }
    }
#undef STG
#undef LDF
}

// ---------------- row log-softmax, wave-per-row, whole row in regs (1R + 1W, NT out) ----------------
__global__ __launch_bounds__(256) void log_softmax_wave(float* __restrict__ y) {
    const int w = threadIdx.x >> 6;
    const int lane = threadIdx.x & 63;
    float* p = y + ((size_t)blockIdx.x * 4 + w) * 1000;
    const bool has3 = lane < 58;             // 250 f32x4 chunks over 64 lanes
    f32x4 v0 = ((const f32x4*)p)[lane];
    f32x4 v1 = ((const f32x4*)p)[lane + 64];
    f32x4 v2 = ((const f32x4*)p)[lane + 128];
    f32x4 v3 = has3 ? ((const f32x4*)p)[lane + 192]
                    : (f32x4){-1e30f, -1e30f, -1e30f, -1e30f};
    float m = fmaxf(fmaxf(fmaxf(v0.x, v0.y), fmaxf(v0.z, v0.w)),
                    fmaxf(fmaxf(v1.x, v1.y), fmaxf(v1.z, v1.w)));
    m = fmaxf(m, fmaxf(fmaxf(v2.x, v2.y), fmaxf(v2.z, v2.w)));
    m = fmaxf(m, fmaxf(fmaxf(v3.x, v3.y), fmaxf(v3.z, v3.w)));
#pragma unroll
    for (int d = 32; d > 0; d >>= 1) m = fmaxf(m, __shfl_xor(m, d));
    float sum = expf(v0.x - m) + expf(v0.y - m) + expf(v0.z - m) + expf(v0.w - m)
              + expf(v1.x - m) + expf(v1.y - m) + expf(v1.z - m) + expf(v1.w - m)
              + expf(v2.x - m) + expf(v2.y - m) + expf(v2.z - m) + expf(v2.w - m)
              + expf(v3.x - m) + expf(v3.y - m) + expf(v3.z - m) + expf(v3.w - m);
#pragma unroll
    for (int d = 32; d > 0; d >>= 1) sum += __shfl_xor(sum, d);
    float lse = m + logf(sum);
    v0.x -= lse; v0.y -= lse; v0.z -= lse; v0.w -= lse;
    v1.x -= lse; v1.y -= lse; v1.z -= lse; v1.w -= lse;
    v2.x -= lse; v2.y -= lse; v2.z -= lse; v2.w -= lse;
    __builtin_nontemporal_store(v0, &((f32x4*)p)[lane]);
    __builtin_nontemporal_store(v1, &((f32x4*)p)[lane + 64]);
    __builtin_nontemporal_store(v2, &((f32x4*)p)[lane + 128]);
    if (has3) {
        v3.x -= lse; v3.y -= lse; v3.z -= lse; v3.w -= lse;
        __builtin_nontemporal_store(v3, &((f32x4*)p)[lane + 192]);
    }
}

extern "C" void kernel_launch(void* const* d_in, const int* in_sizes, int n_in,
                              void* d_out, int out_size, void* d_ws, size_t ws_size,
                              hipStream_t stream) {
    const float* x   = (const float*)d_in[0];
    const float* n0g = (const float*)d_in[1];
    const float* n0b = (const float*)d_in[2];
    const float* S   = (const float*)d_in[3];
    const float* Hm  = (const float*)d_in[4];
    const float* Tt  = (const float*)d_in[5];
    const float* LUT = (const float*)d_in[6];
    const float* W1  = (const float*)d_in[7];
    const float* n1g = (const float*)d_in[9];
    const float* n1b = (const float*)d_in[10];
    const float* W2  = (const float*)d_in[11];
    const float* n2g = (const float*)d_in[13];
    const float* n2b = (const float*)d_in[14];
    const float* W3  = (const float*)d_in[15];
    const float* b3  = (const float*)d_in[16];

    const int B = 16384, IN = 1024, H1 = 2048, H2 = 1024;
    const int NBY0 = 512;

    hipFuncSetAttribute((const void*)&gemm256<true, true, false>,
                        hipFuncAttributeMaxDynamicSharedMemorySize, 131072);
    hipFuncSetAttribute((const void*)&gemm256<true, true, true>,
                        hipFuncAttributeMaxDynamicSharedMemorySize, 131072);
    hipFuncSetAttribute((const void*)&gemm256<false, false, false>,
                        hipFuncAttributeMaxDynamicSharedMemorySize, 131072);

    char* ws = (char*)d_ws;
    size_t off = 0;
    auto alloc = [&](size_t bytes) -> char* {
        char* p = ws + off;
        off += (bytes + 255) & ~(size_t)255;
        return p;
    };
    float* ab0  = (float*)alloc(IN * 2 * sizeof(float));
    float* ab1  = (float*)alloc(H1 * 2 * sizeof(float));
    float* ab2  = (float*)alloc(H2 * 2 * sizeof(float));
    float* part0 = (float*)alloc((size_t)NBY0 * IN * 2 * sizeof(float));
    float* part1 = (float*)alloc((size_t)(B / 256) * H1 * 2 * sizeof(float));
    float* part2 = (float*)alloc((size_t)(B / 256) * H2 * 2 * sizeof(float));
    u16* W1b = (u16*)alloc((size_t)H1 * IN * 2);
    u16* W2b = (u16*)alloc((size_t)H2 * H1 * 2);
    u16* W3b = (u16*)alloc((size_t)1024 * 1024 * 2);
    u16* vb  = (u16*)alloc((size_t)B * IN * 2);        // v, later y2/h2
    u16* y1b = (u16*)alloc((size_t)B * H1 * 2);        // y1, then h1 (in-place)

    float* out0 = (float*)d_out;                        // [16384,1000]
    float* out1 = out0 + (size_t)B * 1000;              // [16384,2048] h1 f32

    // 1: weight cvt + BN0 partial stats (merged leaves)
    leaf_kernel<<<5120 + NBY0, 256, 0, stream>>>(W1, W2, W3, W1b, W2b, W3b, x, part0);

    // 2: BN0 finalize
    col_stats_finalize<<<IN / 32, 256, 0, stream>>>(part0, IN, NBY0, 1.f / B, n0g, n0b, ab0);

    // 3: fused BN0-apply + MM block -> v (bf16)
    mm_block_kernel<<<dim3(B / 256, 32), 256, 0, stream>>>(x, ab0, S, Tt, Hm, LUT, vb);

    // 4: GEMM1 (+BN1 stats): v[B,1024] x W1[2048,1024]^T -> y1 bf16
    gemm256<true, true, false><<<dim3(B / 256, H1 / 256), 512, 131072, stream>>>(
        vb, W1b, y1b, nullptr, part1, B, H1, IN, H1, H1, nullptr, nullptr, 0);

    // 5-6: BN1 finalize + apply (+ReLU), h1 bf16 in-place only (f32 out1 deferred)
    col_stats_finalize<<<H1 / 32, 256, 0, stream>>>(part1, H1, B / 256, 1.f / B, n1g, n1b, ab1);
    bn_relu_apply8<<<B * H1 / 8 / 256, 256, 0, stream>>>(y1b, ab1, H1, B * H1 / 8, nullptr, y1b);

    // 7: GEMM2 (+BN2 stats), grid y = 4 GEMM rows + 2 writer rows (h1 bf16 -> f32 out1, NT)
    gemm256<true, true, true><<<dim3(B / 256, H2 / 256 + 2), 512, 131072, stream>>>(
        y1b, W2b, vb, nullptr, part2, B, H2, H1, H2, H2,
        y1b, out1, (long)B * H1 / 4);

    // 8-9: BN2 finalize + apply (+ReLU), bf16 in-place
    col_stats_finalize<<<H2 / 32, 256, 0, stream>>>(part2, H2, B / 256, 1.f / B, n2g, n2b, ab2);
    bn_relu_apply8<<<B * H2 / 8 / 256, 256, 0, stream>>>(vb, ab2, H2, B * H2 / 8, nullptr, vb);

    // 10: GEMM3: h2[B,1024] x W3pad[1024,1024]^T -> logits f32 + b3
    gemm256<false, false, false><<<dim3(B / 256, 1024 / 256), 512, 131072, stream>>>(
        vb, W3b, out0, b3, nullptr, B, 1024, H2, 1000, 1000, nullptr, nullptr, 0);

    // 11: log-softmax in place (wave per row, single read, NT stores)
    log_softmax_wave<<<B / 4, 256, 0, stream>>>(out0);
}